// Round 8
// baseline (858.590 us; speedup 1.0000x reference)
//
#include <hip/hip_runtime.h>

// CrossAttention: conv1x1 over T (batched GEMM) -> per-head qkv (16x16) ->
// head-vs-head attention (64x64 per (c,t)) with exact entmax15 -> PV.
// v6b: fixes v6's NaN — global_load_lds dest MUST be uniform base + lane*16
// (m104/m108); v6's q_=tid*2+j gave lane stride 32. Now q_=j*512+tid.
// k_gemm: 256^2 tile, BK=32, dbuf 64 KiB => 2 blocks/CU, counted vmcnt(4).
// k_attn (packed-f16 entmax, Newton x2) & transpose/cvt unchanged from v5.
// ws: xT f16 [0,64Mi), X2 f16 [64Mi,128Mi). conv_w f16 scratch in d_out head.

typedef __attribute__((ext_vector_type(8))) _Float16 f16x8;
typedef __attribute__((ext_vector_type(4))) _Float16 f16x4;
typedef __attribute__((ext_vector_type(2))) _Float16 f16x2;
typedef __attribute__((ext_vector_type(4))) float f32x4;

union pk4 { f16x2 h2[2]; f16x4 h4; };

__device__ __forceinline__ f16x2 pkrtz(float a, float b){
  return __builtin_bit_cast(f16x2, __builtin_amdgcn_cvt_pkrtz(a, b));
}

__device__ __forceinline__ void gl_lds16(const void* g, void* l){
  __builtin_amdgcn_global_load_lds((const __attribute__((address_space(1))) void*)g,
                                   (__attribute__((address_space(3))) void*)l, 16, 0, 0);
}

#define ASM_BARRIER()  asm volatile("s_barrier" ::: "memory")
#define WAIT_LGKM0()   asm volatile("s_waitcnt lgkmcnt(0)" ::: "memory")
#define WAIT_VM4()     asm volatile("s_waitcnt vmcnt(4)" ::: "memory")
#define WAIT_VM0()     asm volatile("s_waitcnt vmcnt(0)" ::: "memory")

// ---------------- kernel 0: conv_w f32 -> f16 ----------------
__global__ __launch_bounds__(256) void k_cvt_w(const float* __restrict__ w,
                                               _Float16* __restrict__ wh){
  int i = (blockIdx.x * 256 + threadIdx.x) * 4;
  float4 v = *(const float4*)(w + i);
  f16x4 o = {(_Float16)v.x, (_Float16)v.y, (_Float16)v.z, (_Float16)v.w};
  *(f16x4*)(wh + i) = o;
}

// ------- kernel 1: x_en (c,t,e) f32 -> xT (c,e,t) f16 (64x64 LDS tiles) -------
__global__ __launch_bounds__(256) void k_transpose(const float* __restrict__ x,
                                                   _Float16* __restrict__ xT){
  __shared__ float tile[64][65];
  const int c  = blockIdx.z;
  const int t0 = blockIdx.y * 64;
  const int e0 = blockIdx.x * 64;
  const int tid = threadIdx.x;
  const int c4 = tid & 15;
  const int rb = tid >> 4;
  const float* src = x + ((size_t)c << 20) + (size_t)(t0 + rb) * 1024 + e0 + c4 * 4;
  #pragma unroll
  for (int p = 0; p < 4; ++p){
    float4 v = *(const float4*)(src + (size_t)p * 16 * 1024);
    tile[rb + p*16][c4*4+0] = v.x;
    tile[rb + p*16][c4*4+1] = v.y;
    tile[rb + p*16][c4*4+2] = v.z;
    tile[rb + p*16][c4*4+3] = v.w;
  }
  __syncthreads();
  _Float16* dst = xT + ((size_t)c << 20) + (size_t)(e0 + rb) * 1024 + t0 + c4 * 4;
  #pragma unroll
  for (int p = 0; p < 4; ++p){
    const int el = rb + p*16;
    f16x4 o = {(_Float16)tile[c4*4+0][el], (_Float16)tile[c4*4+1][el],
               (_Float16)tile[c4*4+2][el], (_Float16)tile[c4*4+3][el]};
    *(f16x4*)(dst + (size_t)p * 16 * 1024) = o;
  }
}

// ------- kernel 2: X2[c] = conv_w @ x[c] + conv_b -------
// 256x256 tile, BK=32, 8 waves (2x4), per-wave out 128x64, dbuf LDS 64 KiB
// => 2 blocks/CU. Counted-vmcnt pipeline: stage kt+2 after read-done barrier,
// vmcnt(4) (never 0 until tail). LDS rows 64B; swizzle bits 4-5 both-sides.
// STAGE chunk q_ = j*512 + tid: LDS dest = j*8192 + tid*16 (lane stride 16 —
// required by global_load_lds HW dest rule), row=q_>>2, colchunk=q_&3.
__global__ __launch_bounds__(512, 4) void k_gemm(const _Float16* __restrict__ Aw,
                                                 const _Float16* __restrict__ BxT,
                                                 const float* __restrict__ bias,
                                                 _Float16* __restrict__ X2){
  __shared__ _Float16 smem[32768];   // 64 KiB: [buf(2)][A/B][256 rows x 64 B]
  char* ldsbase = (char*)smem;
  const int tid  = threadIdx.x;
  const int c    = blockIdx.z;
  const int brow = blockIdx.y;
  const int bcol = blockIdx.x;
  const int lane = tid & 63;
  const int wave = tid >> 6;
  const int wrow = wave >> 2;        // 0..1  (128-row half)
  const int wcol = wave & 3;         // 0..3  (64-col quarter)
  const int fr = lane & 15, fq = lane >> 4;
  const int fq16 = fq * 16;                  // byte k-offset within 64B row
  const int swz  = ((fr >> 1) & 3) << 4;     // ds_read swizzle (bits 4-5)

  const char* Ab8 = (const char*)(Aw  + (size_t)(brow*256) * 1024);
  const char* Bb8 = (const char*)(BxT + ((size_t)c << 20) + (size_t)(bcol*256) * 1024);

#define STAGE(kt_, b_) do {                                                    \
    _Pragma("unroll")                                                          \
    for (int j = 0; j < 2; ++j){                                               \
      const int q_   = j*512 + tid;                                            \
      const int row_ = q_ >> 2;                                                \
      const int cl_  = ((q_ & 3)*16) ^ (((row_ >> 1) & 3) << 4);               \
      gl_lds16(Ab8 + (size_t)row_*2048 + (kt_)*64 + cl_,                       \
               ldsbase + (b_)*32768 + q_*16);                                  \
      gl_lds16(Bb8 + (size_t)row_*2048 + (kt_)*64 + cl_,                       \
               ldsbase + (b_)*32768 + 16384 + q_*16);                          \
    }                                                                          \
  } while(0)

  f32x4 acc[8][4];
  #pragma unroll
  for (int m = 0; m < 8; ++m)
    #pragma unroll
    for (int n = 0; n < 4; ++n)
      acc[m][n] = (f32x4){0.f, 0.f, 0.f, 0.f};

#define COMPUTE(b_) do {                                                       \
    const char* pA_ = ldsbase + (b_)*32768;                                    \
    const char* pB_ = pA_ + 16384;                                             \
    f16x8 aF[8], bF[4];                                                        \
    _Pragma("unroll")                                                          \
    for (int m = 0; m < 8; ++m)                                                \
      aF[m] = *(const f16x8*)(pA_ + (wrow*128 + m*16 + fr)*64 + (fq16 ^ swz)); \
    _Pragma("unroll")                                                          \
    for (int n = 0; n < 4; ++n)                                                \
      bF[n] = *(const f16x8*)(pB_ + (wcol*64 + n*16 + fr)*64 + (fq16 ^ swz));  \
    __builtin_amdgcn_s_setprio(1);                                             \
    _Pragma("unroll")                                                          \
    for (int m = 0; m < 8; ++m)                                                \
      _Pragma("unroll")                                                        \
      for (int n = 0; n < 4; ++n)                                              \
        acc[m][n] = __builtin_amdgcn_mfma_f32_16x16x32_f16(aF[m], bF[n],       \
                                                           acc[m][n],0,0,0);   \
    __builtin_amdgcn_s_setprio(0);                                             \
  } while(0)

  // prologue: stage K-tiles 0,1; wait tile0 (tile1's 4 stay in flight)
  STAGE(0, 0);
  STAGE(1, 1);
  WAIT_VM4();
  ASM_BARRIER();

  #pragma unroll 2
  for (int kt = 0; kt < 32; ++kt){
    const int b = kt & 1;
    COMPUTE(b);
    if (kt < 31){
      WAIT_LGKM0();          // this wave done reading buf b
      ASM_BARRIER();         // all waves done reading buf b
      if (kt < 30){
        STAGE(kt + 2, b);    // overwrite buf b (safe after barrier)
        WAIT_VM4();          // kt+1's 4 loads landed (kt+2's in flight)
      } else {
        WAIT_VM0();          // last tile (31) fully landed
      }
      ASM_BARRIER();         // next-tile data visible to all waves
    }
  }

  // epilogue: bias + f16 store
  _Float16* Cb = X2 + ((size_t)c << 20) + (size_t)(brow*256) * 1024 + bcol*256;
  const float* bb = bias + brow*256;
  #pragma unroll
  for (int m = 0; m < 8; ++m){
    #pragma unroll
    for (int r = 0; r < 4; ++r){
      const int orow = wrow*128 + m*16 + fq*4 + r;
      const float bv = bb[orow];
      #pragma unroll
      for (int n = 0; n < 4; ++n){
        const int ocol = wcol*64 + n*16 + fr;
        Cb[(size_t)orow * 1024 + ocol] = (_Float16)(acc[m][n][r] + bv);
      }
    }
  }
#undef STAGE
#undef COMPUTE
}

// ------- kernel 3: MFMA attention, packed-f16 entmax. wave = one (c,t) pair. -------
//   Kt = wk.X^T (D: K[kh=l15][d=g*4+r])  -> scores A-frag
//   Qt = wq.Y^T (D: Q[q =l15][d=g*4+r])  -> scores B-frag (x 1/64 folded)
//   V  = X.wv^T (D: V[kh=g*4+r][d=l15])  -> PV B-frag
//   S^T[kt] = mfma(Kt[kt], Qt)  (D: P[q=l15][kh=kt*16+g*4+r]) -> PV A-frag
// Entmax row q: 16 vals/lane as 8x f16x2; sums via v_dot2_f32_f16 (2x4 split
// chains); 4-lane group reduce (shfl_xor 16,32). Newton x2 from closed-form
// full-support init (exact for full support; quadratic convergence).
__global__ __launch_bounds__(256) void k_attn(const float* __restrict__ y_de,
                                              const _Float16* __restrict__ X2,
                                              const float* __restrict__ wq, const float* __restrict__ bq,
                                              const float* __restrict__ wk, const float* __restrict__ bk,
                                              const float* __restrict__ wv, const float* __restrict__ bv,
                                              float* __restrict__ out){
  const int tid  = threadIdx.x;
  const int wave = tid >> 6, lane = tid & 63;
  const size_t pair = (size_t)blockIdx.x * 4 + wave;
  const int l15 = lane & 15;
  const int g   = lane >> 4;

  f16x4 wqA, wkA, wvB;
  {
    float4 a = *(const float4*)(wq + l15*16 + g*4);
    float4 b = *(const float4*)(wk + l15*16 + g*4);
    float4 c = *(const float4*)(wv + l15*16 + g*4);
    wqA = (f16x4){(_Float16)a.x, (_Float16)a.y, (_Float16)a.z, (_Float16)a.w};
    wkA = (f16x4){(_Float16)b.x, (_Float16)b.y, (_Float16)b.z, (_Float16)b.w};
    wvB = (f16x4){(_Float16)c.x, (_Float16)c.y, (_Float16)c.z, (_Float16)c.w};
  }
  const float4 bqv = *(const float4*)(bq + g*4);
  const float4 bkv = *(const float4*)(bk + g*4);
  const float  bvv = bv[l15];

  const _Float16* xp = X2 + (pair << 10);
  f16x4 xF[4];
  #pragma unroll
  for (int kt = 0; kt < 4; ++kt)
    xF[kt] = *(const f16x4*)(xp + (kt*16 + l15)*16 + g*4);

  f16x4 kF[4], vF[4];
  #pragma unroll
  for (int kt = 0; kt < 4; ++kt){
    f32x4 t = __builtin_amdgcn_mfma_f32_16x16x16f16(wkA, xF[kt], (f32x4){0.f,0.f,0.f,0.f}, 0, 0, 0);
    kF[kt] = (f16x4){(_Float16)(t[0]+bkv.x), (_Float16)(t[1]+bkv.y),
                     (_Float16)(t[2]+bkv.z), (_Float16)(t[3]+bkv.w)};
    f32x4 s = __builtin_amdgcn_mfma_f32_16x16x16f16(xF[kt], wvB, (f32x4){0.f,0.f,0.f,0.f}, 0, 0, 0);
    vF[kt] = (f16x4){(_Float16)(s[0]+bvv), (_Float16)(s[1]+bvv),
                     (_Float16)(s[2]+bvv), (_Float16)(s[3]+bvv)};
  }

  const float* yp = y_de + (pair << 10);
  float* op = out + (pair << 10);

  const f16x2 ones = {(_Float16)1.f, (_Float16)1.f};
  const f16x2 zz   = {(_Float16)0.f, (_Float16)0.f};

  #pragma unroll
  for (int qt = 0; qt < 4; ++qt){
    // Q^T projection; fold 1/(2*sqrt(EMBED)) = 1/64
    float4 yv = *(const float4*)(yp + (qt*16 + l15)*16 + g*4);
    f16x4 yF = {(_Float16)yv.x, (_Float16)yv.y, (_Float16)yv.z, (_Float16)yv.w};
    f32x4 q = __builtin_amdgcn_mfma_f32_16x16x16f16(wqA, yF, (f32x4){0.f,0.f,0.f,0.f}, 0, 0, 0);
    f16x4 qF = {(_Float16)((q[0]+bqv.x)*0.015625f), (_Float16)((q[1]+bqv.y)*0.015625f),
                (_Float16)((q[2]+bqv.z)*0.015625f), (_Float16)((q[3]+bqv.w)*0.015625f)};

    // scores row q = qt*16+l15: 16 entries/lane as 8x packed f16
    f16x2 u8[8];
    #pragma unroll
    for (int kt = 0; kt < 4; ++kt){
      f32x4 s = __builtin_amdgcn_mfma_f32_16x16x16f16(kF[kt], qF, (f32x4){0.f,0.f,0.f,0.f}, 0, 0, 0);
      u8[kt*2+0] = pkrtz(s[0], s[1]);
      u8[kt*2+1] = pkrtz(s[2], s[3]);
    }

    // row max: packed tree + 4-lane group
    f16x2 m0 = __builtin_elementwise_max(u8[0], u8[1]);
    f16x2 m1 = __builtin_elementwise_max(u8[2], u8[3]);
    f16x2 m2 = __builtin_elementwise_max(u8[4], u8[5]);
    f16x2 m3 = __builtin_elementwise_max(u8[6], u8[7]);
    m0 = __builtin_elementwise_max(m0, m1);
    m2 = __builtin_elementwise_max(m2, m3);
    m0 = __builtin_elementwise_max(m0, m2);
    float mx = fmaxf((float)m0[0], (float)m0[1]);
    mx = fmaxf(mx, __shfl_xor(mx, 16));
    mx = fmaxf(mx, __shfl_xor(mx, 32));

    // closed-form full-support init (n=64), 2x split chains
    float S1a = 0.f, S1b = 0.f, S2a = 0.f, S2b = 0.f;
    #pragma unroll
    for (int i = 0; i < 4; ++i){
      S1a = __builtin_amdgcn_fdot2(u8[i],   ones,    S1a, false);
      S1b = __builtin_amdgcn_fdot2(u8[i+4], ones,    S1b, false);
      S2a = __builtin_amdgcn_fdot2(u8[i],   u8[i],   S2a, false);
      S2b = __builtin_amdgcn_fdot2(u8[i+4], u8[i+4], S2b, false);
    }
    float S1 = S1a + S1b, S2 = S2a + S2b;
    S1 += __shfl_xor(S1, 16); S2 += __shfl_xor(S2, 16);
    S1 += __shfl_xor(S1, 32); S2 += __shfl_xor(S2, 32);
    const float mean = S1 * 0.015625f;
    const float ss   = S2 - S1 * mean;          // sum (u-mean)^2
    float delta = fmaxf((1.0f - ss) * 0.015625f, 0.0f);
    float tau = mean - sqrtf(delta);
    tau = fminf(tau, mx - 0.125f);   // tau* <= mx - 1/8  (p_max >= 1/64)
    tau = fmaxf(tau, mx - 1.0f);     // tau* >= mx - 1

    // Newton on g(tau) = sum max(u-tau,0)^2 - 1, packed f16 + dot2, 2 iters
    #pragma unroll
    for (int it = 0; it < 2; ++it){
      f16x2 tt = pkrtz(tau, tau);
      float T1a = 0.f, T1b = 0.f, T2a = 0.f, T2b = 0.f;
      #pragma unroll
      for (int i = 0; i < 4; ++i){
        f16x2 ra = __builtin_elementwise_max(u8[i]   - tt, zz);
        f16x2 rb = __builtin_elementwise_max(u8[i+4] - tt, zz);
        T1a = __builtin_amdgcn_fdot2(ra, ones, T1a, false);
        T1b = __builtin_amdgcn_fdot2(rb, ones, T1b, false);
        T2a = __builtin_amdgcn_fdot2(ra, ra,   T2a, false);
        T2b = __builtin_amdgcn_fdot2(rb, rb,   T2b, false);
      }
      float T1 = T1a + T1b, T2 = T2a + T2b;
      T1 += __shfl_xor(T1, 16); T2 += __shfl_xor(T2, 16);
      T1 += __shfl_xor(T1, 32); T2 += __shfl_xor(T2, 32);
      tau += (T2 - 1.0f) * __builtin_amdgcn_rcpf(2.0f * T1);
    }

    // p = clip(u - tau)^2 packed -> PV A-fragments; PV MFMA
    const f16x2 tt = pkrtz(tau, tau);
    f32x4 o = (f32x4){0.f, 0.f, 0.f, 0.f};
    #pragma unroll
    for (int kt = 0; kt < 4; ++kt){
      f16x2 r0 = __builtin_elementwise_max(u8[kt*2+0] - tt, zz);
      f16x2 r1 = __builtin_elementwise_max(u8[kt*2+1] - tt, zz);
      pk4 pp; pp.h2[0] = r0 * r0; pp.h2[1] = r1 * r1;
      o = __builtin_amdgcn_mfma_f32_16x16x16f16(pp.h4, vF[kt], o, 0, 0, 0);
    }

    #pragma unroll
    for (int r = 0; r < 4; ++r)
      op[(qt*16 + g*4 + r)*16 + l15] = o[r];
  }
}

extern "C" void kernel_launch(void* const* d_in, const int* in_sizes, int n_in,
                              void* d_out, int out_size, void* d_ws, size_t ws_size,
                              hipStream_t stream) {
  (void)in_sizes; (void)n_in; (void)out_size; (void)ws_size;
  const float* x_en   = (const float*)d_in[0];
  const float* y_de   = (const float*)d_in[1];
  const float* wq     = (const float*)d_in[2];
  const float* bq     = (const float*)d_in[3];
  const float* wk     = (const float*)d_in[4];
  const float* bk     = (const float*)d_in[5];
  const float* wv     = (const float*)d_in[6];
  const float* bv     = (const float*)d_in[7];
  const float* conv_w = (const float*)d_in[8];
  const float* conv_b = (const float*)d_in[9];
  float* out = (float*)d_out;

  char* ws = (char*)d_ws;
  _Float16* xT = (_Float16*)ws;                        // 64 MiB f16 (c,e,t)
  _Float16* X2 = (_Float16*)(ws + (size_t)67108864);   // 64 MiB f16 (c,o,e)
  _Float16* wH = (_Float16*)d_out;                     // 2 MiB scratch (overwritten by k_attn)

  k_cvt_w    <<<dim3(1024),       dim3(256), 0, stream>>>(conv_w, wH);
  k_transpose<<<dim3(16, 16, 32), dim3(256), 0, stream>>>(x_en, xT);
  k_gemm     <<<dim3(4, 4, 32),   dim3(512), 0, stream>>>(wH, xT, conv_b, X2);
  k_attn     <<<dim3(8192),       dim3(256), 0, stream>>>(y_de, X2, wq, bq, wk, bk, wv, bv, out);
}

// Round 9
// 187.451 us; speedup vs baseline: 4.5803x; 4.5803x over previous
//
#include <hip/hip_runtime.h>

// CrossAttention: conv1x1 over T (batched GEMM) -> per-head qkv (16x16) ->
// head-vs-head attention (64x64 per (c,t)) with exact entmax15 -> PV.
// v7: v6b's BK=32 / 64KiB-dbuf gemm with __launch_bounds__(512,2) (v6b's
// (512,4) forced VGPR<=128 -> acc[8][4] spilled to scratch: 2.1GB writes,
// 739us). At 128 VGPR (v5's measured count) 2 blocks/CU fit via LDS=64KiB.
// Staging: q_=j*512+tid (lane-stride-16 dest, m104 rule), counted vmcnt(4).
// k_attn (packed-f16 entmax, Newton x2) & transpose/cvt unchanged.
// ws: xT f16 [0,64Mi), X2 f16 [64Mi,128Mi). conv_w f16 scratch in d_out head.

typedef __attribute__((ext_vector_type(8))) _Float16 f16x8;
typedef __attribute__((ext_vector_type(4))) _Float16 f16x4;
typedef __attribute__((ext_vector_type(2))) _Float16 f16x2;
typedef __attribute__((ext_vector_type(4))) float f32x4;

union pk4 { f16x2 h2[2]; f16x4 h4; };

__device__ __forceinline__ f16x2 pkrtz(float a, float b){
  return __builtin_bit_cast(f16x2, __builtin_amdgcn_cvt_pkrtz(a, b));
}

__device__ __forceinline__ void gl_lds16(const void* g, void* l){
  __builtin_amdgcn_global_load_lds((const __attribute__((address_space(1))) void*)g,
                                   (__attribute__((address_space(3))) void*)l, 16, 0, 0);
}

#define ASM_BARRIER()  asm volatile("s_barrier" ::: "memory")
#define WAIT_LGKM0()   asm volatile("s_waitcnt lgkmcnt(0)" ::: "memory")
#define WAIT_VM4()     asm volatile("s_waitcnt vmcnt(4)" ::: "memory")
#define WAIT_VM0()     asm volatile("s_waitcnt vmcnt(0)" ::: "memory")

// ---------------- kernel 0: conv_w f32 -> f16 ----------------
__global__ __launch_bounds__(256) void k_cvt_w(const float* __restrict__ w,
                                               _Float16* __restrict__ wh){
  int i = (blockIdx.x * 256 + threadIdx.x) * 4;
  float4 v = *(const float4*)(w + i);
  f16x4 o = {(_Float16)v.x, (_Float16)v.y, (_Float16)v.z, (_Float16)v.w};
  *(f16x4*)(wh + i) = o;
}

// ------- kernel 1: x_en (c,t,e) f32 -> xT (c,e,t) f16 (64x64 LDS tiles) -------
__global__ __launch_bounds__(256) void k_transpose(const float* __restrict__ x,
                                                   _Float16* __restrict__ xT){
  __shared__ float tile[64][65];
  const int c  = blockIdx.z;
  const int t0 = blockIdx.y * 64;
  const int e0 = blockIdx.x * 64;
  const int tid = threadIdx.x;
  const int c4 = tid & 15;
  const int rb = tid >> 4;
  const float* src = x + ((size_t)c << 20) + (size_t)(t0 + rb) * 1024 + e0 + c4 * 4;
  #pragma unroll
  for (int p = 0; p < 4; ++p){
    float4 v = *(const float4*)(src + (size_t)p * 16 * 1024);
    tile[rb + p*16][c4*4+0] = v.x;
    tile[rb + p*16][c4*4+1] = v.y;
    tile[rb + p*16][c4*4+2] = v.z;
    tile[rb + p*16][c4*4+3] = v.w;
  }
  __syncthreads();
  _Float16* dst = xT + ((size_t)c << 20) + (size_t)(e0 + rb) * 1024 + t0 + c4 * 4;
  #pragma unroll
  for (int p = 0; p < 4; ++p){
    const int el = rb + p*16;
    f16x4 o = {(_Float16)tile[c4*4+0][el], (_Float16)tile[c4*4+1][el],
               (_Float16)tile[c4*4+2][el], (_Float16)tile[c4*4+3][el]};
    *(f16x4*)(dst + (size_t)p * 16 * 1024) = o;
  }
}

// ------- kernel 2: X2[c] = conv_w @ x[c] + conv_b -------
// 256x256 tile, BK=32, 8 waves (2x4), per-wave out 128x64, dbuf LDS 64 KiB.
// Counted-vmcnt pipeline: stage kt+2 after read-done barrier, vmcnt(4).
// LDS rows 64B; bits-4..5 XOR swizzle applied both sides (involution).
// STAGE chunk q_ = j*512 + tid: LDS dest = q_*16 (lane stride 16 — required
// by global_load_lds HW dest rule), row=q_>>2, colchunk=q_&3.
__global__ __launch_bounds__(512, 2) void k_gemm(const _Float16* __restrict__ Aw,
                                                 const _Float16* __restrict__ BxT,
                                                 const float* __restrict__ bias,
                                                 _Float16* __restrict__ X2){
  __shared__ _Float16 smem[32768];   // 64 KiB: [buf(2)][A 16KiB | B 16KiB]
  char* ldsbase = (char*)smem;
  const int tid  = threadIdx.x;
  const int c    = blockIdx.z;
  const int brow = blockIdx.y;
  const int bcol = blockIdx.x;
  const int lane = tid & 63;
  const int wave = tid >> 6;
  const int wrow = wave >> 2;        // 0..1  (128-row half)
  const int wcol = wave & 3;         // 0..3  (64-col quarter)
  const int fr = lane & 15, fq = lane >> 4;
  const int fq16 = fq * 16;                  // byte k-offset within 64B row
  const int swz  = ((fr >> 1) & 3) << 4;     // ds_read swizzle (bits 4-5)

  const char* Ab8 = (const char*)(Aw  + (size_t)(brow*256) * 1024);
  const char* Bb8 = (const char*)(BxT + ((size_t)c << 20) + (size_t)(bcol*256) * 1024);

#define STAGE(kt_, b_) do {                                                    \
    _Pragma("unroll")                                                          \
    for (int j = 0; j < 2; ++j){                                               \
      const int q_   = j*512 + tid;                                            \
      const int row_ = q_ >> 2;                                                \
      const int cl_  = ((q_ & 3)*16) ^ (((row_ >> 1) & 3) << 4);               \
      gl_lds16(Ab8 + (size_t)row_*2048 + (kt_)*64 + cl_,                       \
               ldsbase + (b_)*32768 + q_*16);                                  \
      gl_lds16(Bb8 + (size_t)row_*2048 + (kt_)*64 + cl_,                       \
               ldsbase + (b_)*32768 + 16384 + q_*16);                          \
    }                                                                          \
  } while(0)

  f32x4 acc[8][4];
  #pragma unroll
  for (int m = 0; m < 8; ++m)
    #pragma unroll
    for (int n = 0; n < 4; ++n)
      acc[m][n] = (f32x4){0.f, 0.f, 0.f, 0.f};

#define COMPUTE(b_) do {                                                       \
    const char* pA_ = ldsbase + (b_)*32768;                                    \
    const char* pB_ = pA_ + 16384;                                             \
    f16x8 aF[8], bF[4];                                                        \
    _Pragma("unroll")                                                          \
    for (int m = 0; m < 8; ++m)                                                \
      aF[m] = *(const f16x8*)(pA_ + (wrow*128 + m*16 + fr)*64 + (fq16 ^ swz)); \
    _Pragma("unroll")                                                          \
    for (int n = 0; n < 4; ++n)                                                \
      bF[n] = *(const f16x8*)(pB_ + (wcol*64 + n*16 + fr)*64 + (fq16 ^ swz));  \
    __builtin_amdgcn_s_setprio(1);                                             \
    _Pragma("unroll")                                                          \
    for (int m = 0; m < 8; ++m)                                                \
      _Pragma("unroll")                                                        \
      for (int n = 0; n < 4; ++n)                                              \
        acc[m][n] = __builtin_amdgcn_mfma_f32_16x16x32_f16(aF[m], bF[n],       \
                                                           acc[m][n],0,0,0);   \
    __builtin_amdgcn_s_setprio(0);                                             \
  } while(0)

  // prologue: stage K-tiles 0,1; wait tile0 (tile1's 4 stay in flight)
  STAGE(0, 0);
  STAGE(1, 1);
  WAIT_VM4();
  ASM_BARRIER();

  #pragma unroll 2
  for (int kt = 0; kt < 32; ++kt){
    const int b = kt & 1;
    COMPUTE(b);
    if (kt < 31){
      WAIT_LGKM0();          // this wave done reading buf b
      ASM_BARRIER();         // all waves done reading buf b
      if (kt < 30){
        STAGE(kt + 2, b);    // overwrite buf b (safe after barrier)
        WAIT_VM4();          // kt+1's 4 loads landed (kt+2's in flight)
      } else {
        WAIT_VM0();          // last tile (31) fully landed
      }
      ASM_BARRIER();         // next-tile data visible to all waves
    }
  }

  // epilogue: bias + f16 store
  _Float16* Cb = X2 + ((size_t)c << 20) + (size_t)(brow*256) * 1024 + bcol*256;
  const float* bb = bias + brow*256;
  #pragma unroll
  for (int m = 0; m < 8; ++m){
    #pragma unroll
    for (int r = 0; r < 4; ++r){
      const int orow = wrow*128 + m*16 + fq*4 + r;
      const float bv = bb[orow];
      #pragma unroll
      for (int n = 0; n < 4; ++n){
        const int ocol = wcol*64 + n*16 + fr;
        Cb[(size_t)orow * 1024 + ocol] = (_Float16)(acc[m][n][r] + bv);
      }
    }
  }
#undef STAGE
#undef COMPUTE
}

// ------- kernel 3: MFMA attention, packed-f16 entmax. wave = one (c,t) pair. -------
//   Kt = wk.X^T (D: K[kh=l15][d=g*4+r])  -> scores A-frag
//   Qt = wq.Y^T (D: Q[q =l15][d=g*4+r])  -> scores B-frag (x 1/64 folded)
//   V  = X.wv^T (D: V[kh=g*4+r][d=l15])  -> PV B-frag
//   S^T[kt] = mfma(Kt[kt], Qt)  (D: P[q=l15][kh=kt*16+g*4+r]) -> PV A-frag
// Entmax row q: 16 vals/lane as 8x f16x2; sums via v_dot2_f32_f16 (2x4 split
// chains); 4-lane group reduce (shfl_xor 16,32). Newton x2 from closed-form
// full-support init (exact for full support; quadratic convergence).
__global__ __launch_bounds__(256) void k_attn(const float* __restrict__ y_de,
                                              const _Float16* __restrict__ X2,
                                              const float* __restrict__ wq, const float* __restrict__ bq,
                                              const float* __restrict__ wk, const float* __restrict__ bk,
                                              const float* __restrict__ wv, const float* __restrict__ bv,
                                              float* __restrict__ out){
  const int tid  = threadIdx.x;
  const int wave = tid >> 6, lane = tid & 63;
  const size_t pair = (size_t)blockIdx.x * 4 + wave;
  const int l15 = lane & 15;
  const int g   = lane >> 4;

  f16x4 wqA, wkA, wvB;
  {
    float4 a = *(const float4*)(wq + l15*16 + g*4);
    float4 b = *(const float4*)(wk + l15*16 + g*4);
    float4 c = *(const float4*)(wv + l15*16 + g*4);
    wqA = (f16x4){(_Float16)a.x, (_Float16)a.y, (_Float16)a.z, (_Float16)a.w};
    wkA = (f16x4){(_Float16)b.x, (_Float16)b.y, (_Float16)b.z, (_Float16)b.w};
    wvB = (f16x4){(_Float16)c.x, (_Float16)c.y, (_Float16)c.z, (_Float16)c.w};
  }
  const float4 bqv = *(const float4*)(bq + g*4);
  const float4 bkv = *(const float4*)(bk + g*4);
  const float  bvv = bv[l15];

  const _Float16* xp = X2 + (pair << 10);
  f16x4 xF[4];
  #pragma unroll
  for (int kt = 0; kt < 4; ++kt)
    xF[kt] = *(const f16x4*)(xp + (kt*16 + l15)*16 + g*4);

  f16x4 kF[4], vF[4];
  #pragma unroll
  for (int kt = 0; kt < 4; ++kt){
    f32x4 t = __builtin_amdgcn_mfma_f32_16x16x16f16(wkA, xF[kt], (f32x4){0.f,0.f,0.f,0.f}, 0, 0, 0);
    kF[kt] = (f16x4){(_Float16)(t[0]+bkv.x), (_Float16)(t[1]+bkv.y),
                     (_Float16)(t[2]+bkv.z), (_Float16)(t[3]+bkv.w)};
    f32x4 s = __builtin_amdgcn_mfma_f32_16x16x16f16(xF[kt], wvB, (f32x4){0.f,0.f,0.f,0.f}, 0, 0, 0);
    vF[kt] = (f16x4){(_Float16)(s[0]+bvv), (_Float16)(s[1]+bvv),
                     (_Float16)(s[2]+bvv), (_Float16)(s[3]+bvv)};
  }

  const float* yp = y_de + (pair << 10);
  float* op = out + (pair << 10);

  const f16x2 ones = {(_Float16)1.f, (_Float16)1.f};
  const f16x2 zz   = {(_Float16)0.f, (_Float16)0.f};

  #pragma unroll
  for (int qt = 0; qt < 4; ++qt){
    // Q^T projection; fold 1/(2*sqrt(EMBED)) = 1/64
    float4 yv = *(const float4*)(yp + (qt*16 + l15)*16 + g*4);
    f16x4 yF = {(_Float16)yv.x, (_Float16)yv.y, (_Float16)yv.z, (_Float16)yv.w};
    f32x4 q = __builtin_amdgcn_mfma_f32_16x16x16f16(wqA, yF, (f32x4){0.f,0.f,0.f,0.f}, 0, 0, 0);
    f16x4 qF = {(_Float16)((q[0]+bqv.x)*0.015625f), (_Float16)((q[1]+bqv.y)*0.015625f),
                (_Float16)((q[2]+bqv.z)*0.015625f), (_Float16)((q[3]+bqv.w)*0.015625f)};

    // scores row q = qt*16+l15: 16 entries/lane as 8x packed f16
    f16x2 u8[8];
    #pragma unroll
    for (int kt = 0; kt < 4; ++kt){
      f32x4 s = __builtin_amdgcn_mfma_f32_16x16x16f16(kF[kt], qF, (f32x4){0.f,0.f,0.f,0.f}, 0, 0, 0);
      u8[kt*2+0] = pkrtz(s[0], s[1]);
      u8[kt*2+1] = pkrtz(s[2], s[3]);
    }

    // row max: packed tree + 4-lane group
    f16x2 m0 = __builtin_elementwise_max(u8[0], u8[1]);
    f16x2 m1 = __builtin_elementwise_max(u8[2], u8[3]);
    f16x2 m2 = __builtin_elementwise_max(u8[4], u8[5]);
    f16x2 m3 = __builtin_elementwise_max(u8[6], u8[7]);
    m0 = __builtin_elementwise_max(m0, m1);
    m2 = __builtin_elementwise_max(m2, m3);
    m0 = __builtin_elementwise_max(m0, m2);
    float mx = fmaxf((float)m0[0], (float)m0[1]);
    mx = fmaxf(mx, __shfl_xor(mx, 16));
    mx = fmaxf(mx, __shfl_xor(mx, 32));

    // closed-form full-support init (n=64), 2x split chains
    float S1a = 0.f, S1b = 0.f, S2a = 0.f, S2b = 0.f;
    #pragma unroll
    for (int i = 0; i < 4; ++i){
      S1a = __builtin_amdgcn_fdot2(u8[i],   ones,    S1a, false);
      S1b = __builtin_amdgcn_fdot2(u8[i+4], ones,    S1b, false);
      S2a = __builtin_amdgcn_fdot2(u8[i],   u8[i],   S2a, false);
      S2b = __builtin_amdgcn_fdot2(u8[i+4], u8[i+4], S2b, false);
    }
    float S1 = S1a + S1b, S2 = S2a + S2b;
    S1 += __shfl_xor(S1, 16); S2 += __shfl_xor(S2, 16);
    S1 += __shfl_xor(S1, 32); S2 += __shfl_xor(S2, 32);
    const float mean = S1 * 0.015625f;
    const float ss   = S2 - S1 * mean;          // sum (u-mean)^2
    float delta = fmaxf((1.0f - ss) * 0.015625f, 0.0f);
    float tau = mean - sqrtf(delta);
    tau = fminf(tau, mx - 0.125f);   // tau* <= mx - 1/8  (p_max >= 1/64)
    tau = fmaxf(tau, mx - 1.0f);     // tau* >= mx - 1

    // Newton on g(tau) = sum max(u-tau,0)^2 - 1, packed f16 + dot2, 2 iters
    #pragma unroll
    for (int it = 0; it < 2; ++it){
      f16x2 tt = pkrtz(tau, tau);
      float T1a = 0.f, T1b = 0.f, T2a = 0.f, T2b = 0.f;
      #pragma unroll
      for (int i = 0; i < 4; ++i){
        f16x2 ra = __builtin_elementwise_max(u8[i]   - tt, zz);
        f16x2 rb = __builtin_elementwise_max(u8[i+4] - tt, zz);
        T1a = __builtin_amdgcn_fdot2(ra, ones, T1a, false);
        T1b = __builtin_amdgcn_fdot2(rb, ones, T1b, false);
        T2a = __builtin_amdgcn_fdot2(ra, ra,   T2a, false);
        T2b = __builtin_amdgcn_fdot2(rb, rb,   T2b, false);
      }
      float T1 = T1a + T1b, T2 = T2a + T2b;
      T1 += __shfl_xor(T1, 16); T2 += __shfl_xor(T2, 16);
      T1 += __shfl_xor(T1, 32); T2 += __shfl_xor(T2, 32);
      tau += (T2 - 1.0f) * __builtin_amdgcn_rcpf(2.0f * T1);
    }

    // p = clip(u - tau)^2 packed -> PV A-fragments; PV MFMA
    const f16x2 tt = pkrtz(tau, tau);
    f32x4 o = (f32x4){0.f, 0.f, 0.f, 0.f};
    #pragma unroll
    for (int kt = 0; kt < 4; ++kt){
      f16x2 r0 = __builtin_elementwise_max(u8[kt*2+0] - tt, zz);
      f16x2 r1 = __builtin_elementwise_max(u8[kt*2+1] - tt, zz);
      pk4 pp; pp.h2[0] = r0 * r0; pp.h2[1] = r1 * r1;
      o = __builtin_amdgcn_mfma_f32_16x16x16f16(pp.h4, vF[kt], o, 0, 0, 0);
    }

    #pragma unroll
    for (int r = 0; r < 4; ++r)
      op[(qt*16 + g*4 + r)*16 + l15] = o[r];
  }
}

extern "C" void kernel_launch(void* const* d_in, const int* in_sizes, int n_in,
                              void* d_out, int out_size, void* d_ws, size_t ws_size,
                              hipStream_t stream) {
  (void)in_sizes; (void)n_in; (void)out_size; (void)ws_size;
  const float* x_en   = (const float*)d_in[0];
  const float* y_de   = (const float*)d_in[1];
  const float* wq     = (const float*)d_in[2];
  const float* bq     = (const float*)d_in[3];
  const float* wk     = (const float*)d_in[4];
  const float* bk     = (const float*)d_in[5];
  const float* wv     = (const float*)d_in[6];
  const float* bv     = (const float*)d_in[7];
  const float* conv_w = (const float*)d_in[8];
  const float* conv_b = (const float*)d_in[9];
  float* out = (float*)d_out;

  char* ws = (char*)d_ws;
  _Float16* xT = (_Float16*)ws;                        // 64 MiB f16 (c,e,t)
  _Float16* X2 = (_Float16*)(ws + (size_t)67108864);   // 64 MiB f16 (c,o,e)
  _Float16* wH = (_Float16*)d_out;                     // 2 MiB scratch (overwritten by k_attn)

  k_cvt_w    <<<dim3(1024),       dim3(256), 0, stream>>>(conv_w, wH);
  k_transpose<<<dim3(16, 16, 32), dim3(256), 0, stream>>>(x_en, xT);
  k_gemm     <<<dim3(4, 4, 32),   dim3(512), 0, stream>>>(wH, xT, conv_b, X2);
  k_attn     <<<dim3(8192),       dim3(256), 0, stream>>>(y_de, X2, wq, bq, wk, bk, wv, bv, out);
}

// Round 10
// 185.528 us; speedup vs baseline: 4.6278x; 1.0104x over previous
//
#include <hip/hip_runtime.h>

// CrossAttention: conv1x1 over T (batched GEMM) -> per-head qkv (16x16) ->
// head-vs-head attention (64x64 per (c,t)) with exact entmax15 -> PV.
// v8: k_gemm occupancy fix. v5/v7 stuck at 2 waves/SIMD: acc[8][4]=128 AGPRs
// + ~100 VGPRs = ~228 unified regs/wave. Now 16 waves x (64x64) per 256^2
// tile: acc=64 f32 -> total ~<=128 regs -> 4 waves/SIMD. BK=32, 64KiB dbuf,
// counted vmcnt(2), bits-4..5 both-sides swizzle, lane-stride-16 staging.
// k_attn (packed-f16 entmax, Newton x2) & transpose/cvt unchanged.
// ws: xT f16 [0,64Mi), X2 f16 [64Mi,128Mi). conv_w f16 scratch in d_out head.

typedef __attribute__((ext_vector_type(8))) _Float16 f16x8;
typedef __attribute__((ext_vector_type(4))) _Float16 f16x4;
typedef __attribute__((ext_vector_type(2))) _Float16 f16x2;
typedef __attribute__((ext_vector_type(4))) float f32x4;

union pk4 { f16x2 h2[2]; f16x4 h4; };

__device__ __forceinline__ f16x2 pkrtz(float a, float b){
  return __builtin_bit_cast(f16x2, __builtin_amdgcn_cvt_pkrtz(a, b));
}

__device__ __forceinline__ void gl_lds16(const void* g, void* l){
  __builtin_amdgcn_global_load_lds((const __attribute__((address_space(1))) void*)g,
                                   (__attribute__((address_space(3))) void*)l, 16, 0, 0);
}

#define ASM_BARRIER()  asm volatile("s_barrier" ::: "memory")
#define WAIT_LGKM0()   asm volatile("s_waitcnt lgkmcnt(0)" ::: "memory")
#define WAIT_VM2()     asm volatile("s_waitcnt vmcnt(2)" ::: "memory")
#define WAIT_VM0()     asm volatile("s_waitcnt vmcnt(0)" ::: "memory")

// ---------------- kernel 0: conv_w f32 -> f16 ----------------
__global__ __launch_bounds__(256) void k_cvt_w(const float* __restrict__ w,
                                               _Float16* __restrict__ wh){
  int i = (blockIdx.x * 256 + threadIdx.x) * 4;
  float4 v = *(const float4*)(w + i);
  f16x4 o = {(_Float16)v.x, (_Float16)v.y, (_Float16)v.z, (_Float16)v.w};
  *(f16x4*)(wh + i) = o;
}

// ------- kernel 1: x_en (c,t,e) f32 -> xT (c,e,t) f16 (64x64 LDS tiles) -------
__global__ __launch_bounds__(256) void k_transpose(const float* __restrict__ x,
                                                   _Float16* __restrict__ xT){
  __shared__ float tile[64][65];
  const int c  = blockIdx.z;
  const int t0 = blockIdx.y * 64;
  const int e0 = blockIdx.x * 64;
  const int tid = threadIdx.x;
  const int c4 = tid & 15;
  const int rb = tid >> 4;
  const float* src = x + ((size_t)c << 20) + (size_t)(t0 + rb) * 1024 + e0 + c4 * 4;
  #pragma unroll
  for (int p = 0; p < 4; ++p){
    float4 v = *(const float4*)(src + (size_t)p * 16 * 1024);
    tile[rb + p*16][c4*4+0] = v.x;
    tile[rb + p*16][c4*4+1] = v.y;
    tile[rb + p*16][c4*4+2] = v.z;
    tile[rb + p*16][c4*4+3] = v.w;
  }
  __syncthreads();
  _Float16* dst = xT + ((size_t)c << 20) + (size_t)(e0 + rb) * 1024 + t0 + c4 * 4;
  #pragma unroll
  for (int p = 0; p < 4; ++p){
    const int el = rb + p*16;
    f16x4 o = {(_Float16)tile[c4*4+0][el], (_Float16)tile[c4*4+1][el],
               (_Float16)tile[c4*4+2][el], (_Float16)tile[c4*4+3][el]};
    *(f16x4*)(dst + (size_t)p * 16 * 1024) = o;
  }
}

// ------- kernel 2: X2[c] = conv_w @ x[c] + conv_b -------
// 256x256 tile, BK=32, 16 waves (4x4), per-wave out 64x64 (acc = 64 f32),
// dbuf LDS 64 KiB (A 16K | B 16K per buf). 4 waves/SIMD occupancy target.
// Counted-vmcnt: stage kt+2 after read-done barrier, vmcnt(2) (never 0 until
// tail). LDS rows 64B; bits-4..5 XOR swizzle applied both sides (involution).
// STAGE: 1 A-chunk + 1 B-chunk per thread; dest = tid*16 (lane stride 16 —
// required by global_load_lds HW dest rule), row=tid>>2, colchunk=tid&3.
__global__ __launch_bounds__(1024) void k_gemm(const _Float16* __restrict__ Aw,
                                               const _Float16* __restrict__ BxT,
                                               const float* __restrict__ bias,
                                               _Float16* __restrict__ X2){
  __shared__ _Float16 smem[32768];   // 64 KiB: [buf(2)][A 16KiB | B 16KiB]
  char* ldsbase = (char*)smem;
  const int tid  = threadIdx.x;
  const int c    = blockIdx.z;
  const int brow = blockIdx.y;
  const int bcol = blockIdx.x;
  const int lane = tid & 63;
  const int wave = tid >> 6;
  const int wrow = wave >> 2;        // 0..3  (64-row group)
  const int wcol = wave & 3;         // 0..3  (64-col group)
  const int fr = lane & 15, fq = lane >> 4;
  const int fq16 = fq * 16;                  // byte k-offset within 64B row
  const int swz  = ((fr >> 1) & 3) << 4;     // ds_read swizzle (bits 4-5)

  const char* Ab8 = (const char*)(Aw  + (size_t)(brow*256) * 1024);
  const char* Bb8 = (const char*)(BxT + ((size_t)c << 20) + (size_t)(bcol*256) * 1024);

  const int srow = tid >> 2;                                   // 0..255
  const int scl  = ((tid & 3)*16) ^ (((srow >> 1) & 3) << 4);  // pre-swizzled

#define STAGE(kt_, b_) do {                                                    \
    gl_lds16(Ab8 + (size_t)srow*2048 + (kt_)*64 + scl,                         \
             ldsbase + (b_)*32768 + tid*16);                                   \
    gl_lds16(Bb8 + (size_t)srow*2048 + (kt_)*64 + scl,                         \
             ldsbase + (b_)*32768 + 16384 + tid*16);                           \
  } while(0)

  f32x4 acc[4][4];
  #pragma unroll
  for (int m = 0; m < 4; ++m)
    #pragma unroll
    for (int n = 0; n < 4; ++n)
      acc[m][n] = (f32x4){0.f, 0.f, 0.f, 0.f};

#define COMPUTE(b_) do {                                                       \
    const char* pA_ = ldsbase + (b_)*32768;                                    \
    const char* pB_ = pA_ + 16384;                                             \
    f16x8 aF[4], bF[4];                                                        \
    _Pragma("unroll")                                                          \
    for (int m = 0; m < 4; ++m)                                                \
      aF[m] = *(const f16x8*)(pA_ + (wrow*64 + m*16 + fr)*64 + (fq16 ^ swz));  \
    _Pragma("unroll")                                                          \
    for (int n = 0; n < 4; ++n)                                                \
      bF[n] = *(const f16x8*)(pB_ + (wcol*64 + n*16 + fr)*64 + (fq16 ^ swz));  \
    __builtin_amdgcn_s_setprio(1);                                             \
    _Pragma("unroll")                                                          \
    for (int m = 0; m < 4; ++m)                                                \
      _Pragma("unroll")                                                        \
      for (int n = 0; n < 4; ++n)                                              \
        acc[m][n] = __builtin_amdgcn_mfma_f32_16x16x32_f16(aF[m], bF[n],       \
                                                           acc[m][n],0,0,0);   \
    __builtin_amdgcn_s_setprio(0);                                             \
  } while(0)

  // prologue: stage K-tiles 0,1; wait tile0 (tile1's 2 stay in flight)
  STAGE(0, 0);
  STAGE(1, 1);
  WAIT_VM2();
  ASM_BARRIER();

  #pragma unroll 2
  for (int kt = 0; kt < 32; ++kt){
    const int b = kt & 1;
    COMPUTE(b);
    if (kt < 31){
      WAIT_LGKM0();          // this wave done reading buf b
      ASM_BARRIER();         // all waves done reading buf b
      if (kt < 30){
        STAGE(kt + 2, b);    // overwrite buf b (safe after barrier)
        WAIT_VM2();          // kt+1's 2 loads landed (kt+2's in flight)
      } else {
        WAIT_VM0();          // last tile (31) fully landed
      }
      ASM_BARRIER();         // next-tile data visible to all waves
    }
  }

  // epilogue: bias + f16 store
  _Float16* Cb = X2 + ((size_t)c << 20) + (size_t)(brow*256) * 1024 + bcol*256;
  const float* bb = bias + brow*256;
  #pragma unroll
  for (int m = 0; m < 4; ++m){
    #pragma unroll
    for (int r = 0; r < 4; ++r){
      const int orow = wrow*64 + m*16 + fq*4 + r;
      const float bv = bb[orow];
      #pragma unroll
      for (int n = 0; n < 4; ++n){
        const int ocol = wcol*64 + n*16 + fr;
        Cb[(size_t)orow * 1024 + ocol] = (_Float16)(acc[m][n][r] + bv);
      }
    }
  }
#undef STAGE
#undef COMPUTE
}

// ------- kernel 3: MFMA attention, packed-f16 entmax. wave = one (c,t) pair. -------
//   Kt = wk.X^T (D: K[kh=l15][d=g*4+r])  -> scores A-frag
//   Qt = wq.Y^T (D: Q[q =l15][d=g*4+r])  -> scores B-frag (x 1/64 folded)
//   V  = X.wv^T (D: V[kh=g*4+r][d=l15])  -> PV B-frag
//   S^T[kt] = mfma(Kt[kt], Qt)  (D: P[q=l15][kh=kt*16+g*4+r]) -> PV A-frag
// Entmax row q: 16 vals/lane as 8x f16x2; sums via v_dot2_f32_f16 (2x4 split
// chains); 4-lane group reduce (shfl_xor 16,32). Newton x2 from closed-form
// full-support init (exact for full support; quadratic convergence).
__global__ __launch_bounds__(256) void k_attn(const float* __restrict__ y_de,
                                              const _Float16* __restrict__ X2,
                                              const float* __restrict__ wq, const float* __restrict__ bq,
                                              const float* __restrict__ wk, const float* __restrict__ bk,
                                              const float* __restrict__ wv, const float* __restrict__ bv,
                                              float* __restrict__ out){
  const int tid  = threadIdx.x;
  const int wave = tid >> 6, lane = tid & 63;
  const size_t pair = (size_t)blockIdx.x * 4 + wave;
  const int l15 = lane & 15;
  const int g   = lane >> 4;

  f16x4 wqA, wkA, wvB;
  {
    float4 a = *(const float4*)(wq + l15*16 + g*4);
    float4 b = *(const float4*)(wk + l15*16 + g*4);
    float4 c = *(const float4*)(wv + l15*16 + g*4);
    wqA = (f16x4){(_Float16)a.x, (_Float16)a.y, (_Float16)a.z, (_Float16)a.w};
    wkA = (f16x4){(_Float16)b.x, (_Float16)b.y, (_Float16)b.z, (_Float16)b.w};
    wvB = (f16x4){(_Float16)c.x, (_Float16)c.y, (_Float16)c.z, (_Float16)c.w};
  }
  const float4 bqv = *(const float4*)(bq + g*4);
  const float4 bkv = *(const float4*)(bk + g*4);
  const float  bvv = bv[l15];

  const _Float16* xp = X2 + (pair << 10);
  f16x4 xF[4];
  #pragma unroll
  for (int kt = 0; kt < 4; ++kt)
    xF[kt] = *(const f16x4*)(xp + (kt*16 + l15)*16 + g*4);

  f16x4 kF[4], vF[4];
  #pragma unroll
  for (int kt = 0; kt < 4; ++kt){
    f32x4 t = __builtin_amdgcn_mfma_f32_16x16x16f16(wkA, xF[kt], (f32x4){0.f,0.f,0.f,0.f}, 0, 0, 0);
    kF[kt] = (f16x4){(_Float16)(t[0]+bkv.x), (_Float16)(t[1]+bkv.y),
                     (_Float16)(t[2]+bkv.z), (_Float16)(t[3]+bkv.w)};
    f32x4 s = __builtin_amdgcn_mfma_f32_16x16x16f16(xF[kt], wvB, (f32x4){0.f,0.f,0.f,0.f}, 0, 0, 0);
    vF[kt] = (f16x4){(_Float16)(s[0]+bvv), (_Float16)(s[1]+bvv),
                     (_Float16)(s[2]+bvv), (_Float16)(s[3]+bvv)};
  }

  const float* yp = y_de + (pair << 10);
  float* op = out + (pair << 10);

  const f16x2 ones = {(_Float16)1.f, (_Float16)1.f};
  const f16x2 zz   = {(_Float16)0.f, (_Float16)0.f};

  #pragma unroll
  for (int qt = 0; qt < 4; ++qt){
    // Q^T projection; fold 1/(2*sqrt(EMBED)) = 1/64
    float4 yv = *(const float4*)(yp + (qt*16 + l15)*16 + g*4);
    f16x4 yF = {(_Float16)yv.x, (_Float16)yv.y, (_Float16)yv.z, (_Float16)yv.w};
    f32x4 q = __builtin_amdgcn_mfma_f32_16x16x16f16(wqA, yF, (f32x4){0.f,0.f,0.f,0.f}, 0, 0, 0);
    f16x4 qF = {(_Float16)((q[0]+bqv.x)*0.015625f), (_Float16)((q[1]+bqv.y)*0.015625f),
                (_Float16)((q[2]+bqv.z)*0.015625f), (_Float16)((q[3]+bqv.w)*0.015625f)};

    // scores row q = qt*16+l15: 16 entries/lane as 8x packed f16
    f16x2 u8[8];
    #pragma unroll
    for (int kt = 0; kt < 4; ++kt){
      f32x4 s = __builtin_amdgcn_mfma_f32_16x16x16f16(kF[kt], qF, (f32x4){0.f,0.f,0.f,0.f}, 0, 0, 0);
      u8[kt*2+0] = pkrtz(s[0], s[1]);
      u8[kt*2+1] = pkrtz(s[2], s[3]);
    }

    // row max: packed tree + 4-lane group
    f16x2 m0 = __builtin_elementwise_max(u8[0], u8[1]);
    f16x2 m1 = __builtin_elementwise_max(u8[2], u8[3]);
    f16x2 m2 = __builtin_elementwise_max(u8[4], u8[5]);
    f16x2 m3 = __builtin_elementwise_max(u8[6], u8[7]);
    m0 = __builtin_elementwise_max(m0, m1);
    m2 = __builtin_elementwise_max(m2, m3);
    m0 = __builtin_elementwise_max(m0, m2);
    float mx = fmaxf((float)m0[0], (float)m0[1]);
    mx = fmaxf(mx, __shfl_xor(mx, 16));
    mx = fmaxf(mx, __shfl_xor(mx, 32));

    // closed-form full-support init (n=64), 2x split chains
    float S1a = 0.f, S1b = 0.f, S2a = 0.f, S2b = 0.f;
    #pragma unroll
    for (int i = 0; i < 4; ++i){
      S1a = __builtin_amdgcn_fdot2(u8[i],   ones,    S1a, false);
      S1b = __builtin_amdgcn_fdot2(u8[i+4], ones,    S1b, false);
      S2a = __builtin_amdgcn_fdot2(u8[i],   u8[i],   S2a, false);
      S2b = __builtin_amdgcn_fdot2(u8[i+4], u8[i+4], S2b, false);
    }
    float S1 = S1a + S1b, S2 = S2a + S2b;
    S1 += __shfl_xor(S1, 16); S2 += __shfl_xor(S2, 16);
    S1 += __shfl_xor(S1, 32); S2 += __shfl_xor(S2, 32);
    const float mean = S1 * 0.015625f;
    const float ss   = S2 - S1 * mean;          // sum (u-mean)^2
    float delta = fmaxf((1.0f - ss) * 0.015625f, 0.0f);
    float tau = mean - sqrtf(delta);
    tau = fminf(tau, mx - 0.125f);   // tau* <= mx - 1/8  (p_max >= 1/64)
    tau = fmaxf(tau, mx - 1.0f);     // tau* >= mx - 1

    // Newton on g(tau) = sum max(u-tau,0)^2 - 1, packed f16 + dot2, 2 iters
    #pragma unroll
    for (int it = 0; it < 2; ++it){
      f16x2 tt = pkrtz(tau, tau);
      float T1a = 0.f, T1b = 0.f, T2a = 0.f, T2b = 0.f;
      #pragma unroll
      for (int i = 0; i < 4; ++i){
        f16x2 ra = __builtin_elementwise_max(u8[i]   - tt, zz);
        f16x2 rb = __builtin_elementwise_max(u8[i+4] - tt, zz);
        T1a = __builtin_amdgcn_fdot2(ra, ones, T1a, false);
        T1b = __builtin_amdgcn_fdot2(rb, ones, T1b, false);
        T2a = __builtin_amdgcn_fdot2(ra, ra,   T2a, false);
        T2b = __builtin_amdgcn_fdot2(rb, rb,   T2b, false);
      }
      float T1 = T1a + T1b, T2 = T2a + T2b;
      T1 += __shfl_xor(T1, 16); T2 += __shfl_xor(T2, 16);
      T1 += __shfl_xor(T1, 32); T2 += __shfl_xor(T2, 32);
      tau += (T2 - 1.0f) * __builtin_amdgcn_rcpf(2.0f * T1);
    }

    // p = clip(u - tau)^2 packed -> PV A-fragments; PV MFMA
    const f16x2 tt = pkrtz(tau, tau);
    f32x4 o = (f32x4){0.f, 0.f, 0.f, 0.f};
    #pragma unroll
    for (int kt = 0; kt < 4; ++kt){
      f16x2 r0 = __builtin_elementwise_max(u8[kt*2+0] - tt, zz);
      f16x2 r1 = __builtin_elementwise_max(u8[kt*2+1] - tt, zz);
      pk4 pp; pp.h2[0] = r0 * r0; pp.h2[1] = r1 * r1;
      o = __builtin_amdgcn_mfma_f32_16x16x16f16(pp.h4, vF[kt], o, 0, 0, 0);
    }

    #pragma unroll
    for (int r = 0; r < 4; ++r)
      op[(qt*16 + g*4 + r)*16 + l15] = o[r];
  }
}

extern "C" void kernel_launch(void* const* d_in, const int* in_sizes, int n_in,
                              void* d_out, int out_size, void* d_ws, size_t ws_size,
                              hipStream_t stream) {
  (void)in_sizes; (void)n_in; (void)out_size; (void)ws_size;
  const float* x_en   = (const float*)d_in[0];
  const float* y_de   = (const float*)d_in[1];
  const float* wq     = (const float*)d_in[2];
  const float* bq     = (const float*)d_in[3];
  const float* wk     = (const float*)d_in[4];
  const float* bk     = (const float*)d_in[5];
  const float* wv     = (const float*)d_in[6];
  const float* bv     = (const float*)d_in[7];
  const float* conv_w = (const float*)d_in[8];
  const float* conv_b = (const float*)d_in[9];
  float* out = (float*)d_out;

  char* ws = (char*)d_ws;
  _Float16* xT = (_Float16*)ws;                        // 64 MiB f16 (c,e,t)
  _Float16* X2 = (_Float16*)(ws + (size_t)67108864);   // 64 MiB f16 (c,o,e)
  _Float16* wH = (_Float16*)d_out;                     // 2 MiB scratch (overwritten by k_attn)

  k_cvt_w    <<<dim3(1024),       dim3(256),  0, stream>>>(conv_w, wH);
  k_transpose<<<dim3(16, 16, 32), dim3(256),  0, stream>>>(x_en, xT);
  k_gemm     <<<dim3(4, 4, 32),   dim3(1024), 0, stream>>>(wH, xT, conv_b, X2);
  k_attn     <<<dim3(8192),       dim3(256),  0, stream>>>(y_de, X2, wq, bq, wk, bk, wv, bv, out);
}